// Round 1
// baseline (2909.406 us; speedup 1.0000x reference)
//
#include <hip/hip_runtime.h>
#include <math.h>

#define NNODES 8000
#define NP1    8001
#define H      256
#define G3     768
#define CAP    128
#define TSTEPS 8
#define MTOT   (2*NP1)   // 16002
#define NROWBLK 251      // ceil(8001/32)

// ---------------- build ELL adjacency (row -> list of sender cols) ----------------
__global__ __launch_bounds__(256) void build_ell_kernel(
    const float* __restrict__ adj_b, const float* __restrict__ adj_a,
    int* __restrict__ counts, int* __restrict__ colidx)
{
  long long tid = (long long)blockIdx.x * blockDim.x + threadIdx.x;
  long long e = tid * 4;
  const long long PER = (long long)NNODES * NNODES; // 64,000,000
  int g = (int)(e / PER);
  long long rem = e - (long long)g * PER;
  int row  = (int)(rem / NNODES);
  int col0 = (int)(rem - (long long)row * NNODES);
  const float* adj = g ? adj_a : adj_b;
  float4 v = *(const float4*)(adj + rem);
  int rbase = g * NNODES + row;
  #pragma unroll
  for (int u = 0; u < 4; ++u) {
    float val = (&v.x)[u];
    if (val != 0.0f) {
      int k = atomicAdd(&counts[rbase], 1);
      if (k < CAP) colidx[(long long)rbase * CAP + k] = col0 + u;
    }
  }
}

// ---------------- W_c = W_ih @ W_lin  [768,256], b_c = W_ih @ b_lin [768] ----------
__global__ __launch_bounds__(256) void wc_kernel(
    const float* __restrict__ Wih, const float* __restrict__ Wlin,
    const float* __restrict__ blin, float* __restrict__ Wc, float* __restrict__ bc)
{
  __shared__ float srow[H];
  __shared__ float red[256];
  int r = blockIdx.x;     // 0..767
  int t = threadIdx.x;    // 0..255
  srow[t] = Wih[(size_t)r * H + t];
  __syncthreads();
  float acc = 0.f;
  #pragma unroll 8
  for (int k = 0; k < H; ++k) acc += srow[k] * Wlin[(size_t)k * H + t];
  Wc[(size_t)r * H + t] = acc;
  red[t] = srow[t] * blin[t];
  __syncthreads();
  for (int s = 128; s > 0; s >>= 1) { if (t < s) red[t] += red[t + s]; __syncthreads(); }
  if (t == 0) bc[r] = red[0];
}

// ---------------- init h (copy x, zero supernode) + colsum(h) into cs0 -------------
__global__ __launch_bounds__(256) void init_h_kernel(
    const float* __restrict__ bx, const float* __restrict__ ax,
    float* __restrict__ h, float* __restrict__ cs0)
{
  int b = blockIdx.x;
  int g = b / NROWBLK, rb = b - g * NROWBLK;
  int t = threadIdx.x;
  const float* x = g ? ax : bx;
  float local = 0.f;
  for (int q = 0; q < 32; ++q) {
    int r = rb * 32 + q;
    if (r >= NP1) break;
    size_t off = ((size_t)g * NP1 + r) * H + t;
    if (r < NNODES) { float v = x[(size_t)r * H + t]; h[off] = v; local += v; }
    else h[off] = 0.f;
  }
  atomicAdd(&cs0[g * H + t], local);
}

// ---------------- hagg = A @ h  (ELL gather; supernode row = colsum) ---------------
__global__ __launch_bounds__(256) void spmm_kernel(
    const float* __restrict__ h, float* __restrict__ hagg,
    const int* __restrict__ counts, const int* __restrict__ colidx,
    const float* __restrict__ cs)
{
  int b = blockIdx.x;             // 0..16001
  int g = b / NP1, r = b - g * NP1;
  int t = threadIdx.x;
  size_t outoff = ((size_t)g * NP1 + r) * H + t;
  if (r == NNODES) { hagg[outoff] = cs[g * H + t]; return; }
  int rbase = g * NNODES + r;
  int cnt = counts[rbase];
  const int* cols = colidx + (long long)rbase * CAP;
  const float* hg = h + (size_t)g * NP1 * H;
  float acc = 0.f;
  for (int k = 0; k < cnt; ++k) {
    int c = cols[k];
    acc += hg[(size_t)c * H + t];
  }
  hagg[outoff] = acc;
}

// ---------------- G = [ hagg @ Wc^T | h @ Whh^T ]  [16002, 1536] -------------------
#define BM 128
#define BN 128
#define BK 32
__global__ __launch_bounds__(256) void gemm_kernel(
    const float* __restrict__ hagg, const float* __restrict__ h,
    const float* __restrict__ Wc, const float* __restrict__ Whh,
    float* __restrict__ G)
{
  int mt = blockIdx.x;   // 0..125
  int ct = blockIdx.y;   // 0..11
  const float* A; const float* W; int wr0; int colbase;
  if (ct < 6) { A = hagg; W = Wc;  wr0 = ct * BN;       colbase = ct * BN; }
  else        { A = h;    W = Whh; wr0 = (ct - 6) * BN; colbase = G3 + (ct - 6) * BN; }
  int m0 = mt * BM;

  __shared__ float As[BK][BM + 4];
  __shared__ float Bs[BK][BN + 4];
  int tid = threadIdx.x;
  int tm = tid >> 4, tn = tid & 15;   // 16x16 threads, 8x8 each
  float acc[8][8] = {};
  int ly = tid >> 3;   // 0..31
  int lx = tid & 7;    // 0..7 -> k offset lx*4

  for (int k0 = 0; k0 < H; k0 += BK) {
    float4 a[4], bb[4];
    #pragma unroll
    for (int i = 0; i < 4; ++i) {
      int row = m0 + ly + i * 32;
      a[i] = (row < MTOT) ? *(const float4*)&A[(size_t)row * H + k0 + lx * 4]
                          : make_float4(0.f, 0.f, 0.f, 0.f);
      bb[i] = *(const float4*)&W[(size_t)(wr0 + ly + i * 32) * H + k0 + lx * 4];
    }
    __syncthreads();
    #pragma unroll
    for (int i = 0; i < 4; ++i) {
      As[lx * 4 + 0][ly + i * 32] = a[i].x;  As[lx * 4 + 1][ly + i * 32] = a[i].y;
      As[lx * 4 + 2][ly + i * 32] = a[i].z;  As[lx * 4 + 3][ly + i * 32] = a[i].w;
      Bs[lx * 4 + 0][ly + i * 32] = bb[i].x; Bs[lx * 4 + 1][ly + i * 32] = bb[i].y;
      Bs[lx * 4 + 2][ly + i * 32] = bb[i].z; Bs[lx * 4 + 3][ly + i * 32] = bb[i].w;
    }
    __syncthreads();
    #pragma unroll
    for (int kk = 0; kk < BK; ++kk) {
      float av[8], bv[8];
      *(float4*)&av[0] = *(const float4*)&As[kk][tm * 8];
      *(float4*)&av[4] = *(const float4*)&As[kk][tm * 8 + 4];
      *(float4*)&bv[0] = *(const float4*)&Bs[kk][tn * 8];
      *(float4*)&bv[4] = *(const float4*)&Bs[kk][tn * 8 + 4];
      #pragma unroll
      for (int i = 0; i < 8; ++i)
        #pragma unroll
        for (int j = 0; j < 8; ++j)
          acc[i][j] += av[i] * bv[j];
    }
  }
  #pragma unroll
  for (int i = 0; i < 8; ++i) {
    int row = m0 + tm * 8 + i;
    if (row < MTOT) {
      float4 v0 = make_float4(acc[i][0], acc[i][1], acc[i][2], acc[i][3]);
      float4 v1 = make_float4(acc[i][4], acc[i][5], acc[i][6], acc[i][7]);
      *(float4*)&G[(size_t)row * 1536 + colbase + tn * 8]     = v0;
      *(float4*)&G[(size_t)row * 1536 + colbase + tn * 8 + 4] = v1;
    }
  }
}

// ---------------- GRU elementwise + colsum(h_new) into cs_next ---------------------
__global__ __launch_bounds__(256) void gru_kernel(
    const float* __restrict__ G, float* __restrict__ h,
    const int* __restrict__ counts,
    const float* __restrict__ bc, const float* __restrict__ bih,
    const float* __restrict__ bhh, float* __restrict__ cs_next)
{
  int b = blockIdx.x;
  int g = b / NROWBLK, rb = b - g * NROWBLK;
  int t = threadIdx.x;
  float bc_r = bc[t], bc_z = bc[H + t], bc_n = bc[2 * H + t];
  float bih_r = bih[t], bih_z = bih[H + t], bih_n = bih[2 * H + t];
  float bhh_r = bhh[t], bhh_z = bhh[H + t], bhh_n = bhh[2 * H + t];
  float local = 0.f;
  for (int q = 0; q < 32; ++q) {
    int r = rb * 32 + q;
    if (r >= NP1) break;
    size_t rowoff = ((size_t)g * NP1 + r) * 1536;
    float deg = (r < NNODES) ? (float)counts[g * NNODES + r] : (float)NNODES;
    float ir  = G[rowoff + t]         + deg * bc_r + bih_r;
    float iz  = G[rowoff + H + t]     + deg * bc_z + bih_z;
    float in_ = G[rowoff + 2 * H + t] + deg * bc_n + bih_n;
    float hr  = G[rowoff + 3 * H + t] + bhh_r;
    float hz  = G[rowoff + 4 * H + t] + bhh_z;
    float hn  = G[rowoff + 5 * H + t] + bhh_n;
    float rg = 1.f / (1.f + expf(-(ir + hr)));
    float z  = 1.f / (1.f + expf(-(iz + hz)));
    float n  = tanhf(in_ + rg * hn);
    size_t hoff = ((size_t)g * NP1 + r) * H + t;
    float hp = h[hoff];
    float hnew = (1.f - z) * n + z * hp;
    h[hoff] = hnew;
    if (r < NNODES) local += hnew;
  }
  atomicAdd(&cs_next[g * H + t], local);
}

// ---------------- final logits + log_softmax ---------------------------------------
__global__ __launch_bounds__(256) void final_kernel(
    const float* __restrict__ h, const float* __restrict__ Wfc,
    const float* __restrict__ bfc, float* __restrict__ out)
{
  __shared__ float red0[256];
  __shared__ float red1[256];
  int t = threadIdx.x;
  float sn0 = h[(size_t)NNODES * H + t];              // b supernode
  float sn1 = h[((size_t)NP1 + NNODES) * H + t];      // a supernode
  red0[t] = sn0 * Wfc[t]       + sn1 * Wfc[H + t];
  red1[t] = sn0 * Wfc[512 + t] + sn1 * Wfc[512 + H + t];
  __syncthreads();
  for (int s = 128; s > 0; s >>= 1) {
    if (t < s) { red0[t] += red0[t + s]; red1[t] += red1[t + s]; }
    __syncthreads();
  }
  if (t == 0) {
    float l0 = red0[0] + bfc[0], l1 = red1[0] + bfc[1];
    float m = fmaxf(l0, l1);
    float lse = m + logf(expf(l0 - m) + expf(l1 - m));
    out[0] = l0 - lse;
    out[1] = l1 - lse;
  }
}

extern "C" void kernel_launch(void* const* d_in, const int* in_sizes, int n_in,
                              void* d_out, int out_size, void* d_ws, size_t ws_size,
                              hipStream_t stream) {
  const float* b_x   = (const float*)d_in[0];
  const float* b_adj = (const float*)d_in[1];
  const float* a_x   = (const float*)d_in[2];
  const float* a_adj = (const float*)d_in[3];
  const float* Wlin  = (const float*)d_in[4];
  const float* blin  = (const float*)d_in[5];
  const float* Wih   = (const float*)d_in[6];
  const float* bih   = (const float*)d_in[7];
  const float* Whh   = (const float*)d_in[8];
  const float* bhh   = (const float*)d_in[9];
  const float* Wfc   = (const float*)d_in[10];
  const float* bfc   = (const float*)d_in[11];
  float* out = (float*)d_out;

  char* ws = (char*)d_ws;
  size_t off = 0;
  auto alloc = [&](size_t bytes) {
    void* p = ws + off;
    off += (bytes + 255) & ~(size_t)255;
    return p;
  };
  float* h    = (float*)alloc((size_t)MTOT * H * 4);        // 16.4 MB
  float* hagg = (float*)alloc((size_t)MTOT * H * 4);        // 16.4 MB
  float* G    = (float*)alloc((size_t)MTOT * 1536 * 4);     // 98.3 MB
  float* Wc   = (float*)alloc((size_t)G3 * H * 4);          // 0.8 MB
  float* bc   = (float*)alloc((size_t)G3 * 4);
  int* colidx = (int*)alloc((size_t)2 * NNODES * CAP * 4);  // 8.2 MB
  int* counts = (int*)alloc((size_t)2 * NNODES * 4);
  float* cs   = (float*)alloc((size_t)(TSTEPS + 1) * 2 * H * 4);

  hipMemsetAsync(counts, 0, (size_t)2 * NNODES * 4, stream);
  hipMemsetAsync(cs, 0, (size_t)(TSTEPS + 1) * 2 * H * 4, stream);

  // 2 * 64e6 elems / 4 per thread / 256 per block = 125000 blocks
  build_ell_kernel<<<125000, 256, 0, stream>>>(b_adj, a_adj, counts, colidx);
  wc_kernel<<<G3, 256, 0, stream>>>(Wih, Wlin, blin, Wc, bc);
  init_h_kernel<<<2 * NROWBLK, 256, 0, stream>>>(b_x, a_x, h, cs);

  for (int t = 0; t < TSTEPS; ++t) {
    spmm_kernel<<<MTOT, 256, 0, stream>>>(h, hagg, counts, colidx, cs + t * 2 * H);
    gemm_kernel<<<dim3(126, 12), 256, 0, stream>>>(hagg, h, Wc, Whh, G);
    gru_kernel<<<2 * NROWBLK, 256, 0, stream>>>(G, h, counts, bc, bih, bhh,
                                                cs + (t + 1) * 2 * H);
  }
  final_kernel<<<1, 256, 0, stream>>>(h, Wfc, bfc, out);
}

// Round 2
// 1515.407 us; speedup vs baseline: 1.9199x; 1.9199x over previous
//
#include <hip/hip_runtime.h>
#include <hip/hip_bf16.h>
#include <math.h>

#define NNODES 8000
#define NP1    8001
#define H      256
#define G3     768
#define CAP    64
#define TSTEPS 8
#define MTOT   (2*NP1)    // 16002
#define MPAD   16128      // 126 * 128
#define NROWBLK 251       // ceil(8001/32)

typedef __attribute__((ext_vector_type(8))) short short8;
typedef __attribute__((ext_vector_type(4))) float floatx4;

// ---------------- build ELL adjacency (row -> list of sender cols) ----------------
__global__ __launch_bounds__(256) void build_ell_kernel(
    const float* __restrict__ adj_b, const float* __restrict__ adj_a,
    int* __restrict__ counts, int* __restrict__ colidx)
{
  long long tid = (long long)blockIdx.x * blockDim.x + threadIdx.x;
  long long e = tid * 4;
  const long long PER = (long long)NNODES * NNODES; // 64,000,000
  int g = (int)(e / PER);
  long long rem = e - (long long)g * PER;
  int row  = (int)(rem / NNODES);
  int col0 = (int)(rem - (long long)row * NNODES);
  const float* adj = g ? adj_a : adj_b;
  float4 v = *(const float4*)(adj + rem);
  int rbase = g * NNODES + row;
  #pragma unroll
  for (int u = 0; u < 4; ++u) {
    float val = (&v.x)[u];
    if (val != 0.0f) {
      int k = atomicAdd(&counts[rbase], 1);
      if (k < CAP) colidx[(long long)rbase * CAP + k] = col0 + u;
    }
  }
}

// ------- Wcat[0:768]=bf16(W_ih@W_lin), Wcat[768:1536]=bf16(W_hh); bc=W_ih@b_lin ----
__global__ __launch_bounds__(256) void weights_kernel(
    const float* __restrict__ Wih, const float* __restrict__ Wlin,
    const float* __restrict__ blin, const float* __restrict__ Whh,
    __hip_bfloat16* __restrict__ Wcat, float* __restrict__ bc)
{
  __shared__ float srow[H];
  __shared__ float red[256];
  int r = blockIdx.x;     // 0..1535
  int t = threadIdx.x;    // 0..255
  if (r < G3) {
    srow[t] = Wih[(size_t)r * H + t];
    __syncthreads();
    float acc = 0.f;
    #pragma unroll 8
    for (int k = 0; k < H; ++k) acc += srow[k] * Wlin[(size_t)k * H + t];
    Wcat[(size_t)r * H + t] = __float2bfloat16(acc);
    red[t] = srow[t] * blin[t];
    __syncthreads();
    for (int s = 128; s > 0; s >>= 1) { if (t < s) red[t] += red[t + s]; __syncthreads(); }
    if (t == 0) bc[r] = red[0];
  } else {
    Wcat[(size_t)r * H + t] = __float2bfloat16(Whh[(size_t)(r - G3) * H + t]);
  }
}

// ---------------- init h (fp32 + bf16), zero supernode, colsum -> cs0 --------------
__global__ __launch_bounds__(256) void init_h_kernel(
    const float* __restrict__ bx, const float* __restrict__ ax,
    float* __restrict__ h, __hip_bfloat16* __restrict__ hbf, float* __restrict__ cs0)
{
  int b = blockIdx.x;
  int g = b / NROWBLK, rb = b - g * NROWBLK;
  int t = threadIdx.x;
  const float* x = g ? ax : bx;
  float local = 0.f;
  for (int q = 0; q < 32; ++q) {
    int r = rb * 32 + q;
    if (r >= NP1) break;
    size_t off = ((size_t)g * NP1 + r) * H + t;
    float v = 0.f;
    if (r < NNODES) { v = x[(size_t)r * H + t]; local += v; }
    h[off] = v;
    hbf[off] = __float2bfloat16(v);
  }
  atomicAdd(&cs0[g * H + t], local);
}

// ---------------- hagg_bf = bf16(A @ h)  (ELL gather; supernode = colsum) ----------
__global__ __launch_bounds__(256) void spmm_kernel(
    const __hip_bfloat16* __restrict__ hbf, __hip_bfloat16* __restrict__ haggbf,
    const int* __restrict__ counts, const int* __restrict__ colidx,
    const float* __restrict__ cs)
{
  int b = blockIdx.x;             // 0..16001
  int g = b / NP1, r = b - g * NP1;
  int t = threadIdx.x;
  size_t outoff = ((size_t)g * NP1 + r) * H + t;
  if (r == NNODES) { haggbf[outoff] = __float2bfloat16(cs[g * H + t]); return; }
  int rbase = g * NNODES + r;
  int cnt = counts[rbase];
  const int* cols = colidx + (long long)rbase * CAP;
  const __hip_bfloat16* hg = hbf + (size_t)g * NP1 * H;
  float acc = 0.f;
  for (int k = 0; k < cnt; ++k) {
    int c = cols[k];
    acc += __bfloat162float(hg[(size_t)c * H + t]);
  }
  haggbf[outoff] = __float2bfloat16(acc);
}

// ---------------- G = [ hagg @ Wc^T | h @ Whh^T ]  (bf16 MFMA, fp32 out) -----------
// A-operand [MPAD,256] bf16 row-major, B = Wcat [1536,256] bf16 row-major (NT GEMM).
// 128x128 tile, BK=32, 4 waves each 64x64 (4x4 grid of 16x16x32 MFMAs).
// global_load_lds(16B) with XOR chunk swizzle (c ^ ((row>>1)&3)) so both the DMA
// write (lane-contiguous, enforced) and the frag ds_read_b128 are conflict-free
// (2-way max = free).
__global__ __launch_bounds__(256) void mfma_gemm_kernel(
    const __hip_bfloat16* __restrict__ haggbf, const __hip_bfloat16* __restrict__ hbf,
    const __hip_bfloat16* __restrict__ Wcat, float* __restrict__ G)
{
  __shared__ __align__(16) short lsA[128 * 32];
  __shared__ __align__(16) short lsB[128 * 32];
  int by = blockIdx.y;                     // 0..11
  const short* A = (const short*)((by < 6) ? haggbf : hbf);
  const short* B = (const short*)Wcat + (size_t)by * 128 * H;
  int m0 = blockIdx.x * 128;
  int t = threadIdx.x;
  int w = t >> 6, l = t & 63;
  int lr = l >> 2;        // staging: row within 16-row group
  int lc = l & 3;         // staging: chunk slot
  int wm = (w & 1) * 64, wn = (w >> 1) * 64;
  int q = l >> 4, lm = l & 15;
  floatx4 acc[4][4] = {};

  for (int k0 = 0; k0 < H; k0 += 32) {
    #pragma unroll
    for (int j = 0; j < 2; ++j) {
      int r = j * 64 + w * 16 + lr;
      int c = lc ^ ((r >> 1) & 3);
      const short* ga = A + (size_t)(m0 + r) * H + k0 + c * 8;
      const short* gb = B + (size_t)r * H + k0 + c * 8;
      short* la = lsA + (j * 64 + w * 16) * 32;   // wave-uniform base
      short* lb = lsB + (j * 64 + w * 16) * 32;
      __builtin_amdgcn_global_load_lds((const __attribute__((address_space(1))) void*)ga,
                                       (__attribute__((address_space(3))) void*)la, 16, 0, 0);
      __builtin_amdgcn_global_load_lds((const __attribute__((address_space(1))) void*)gb,
                                       (__attribute__((address_space(3))) void*)lb, 16, 0, 0);
    }
    __syncthreads();
    short8 af[4], bfr[4];
    #pragma unroll
    for (int i = 0; i < 4; ++i) {
      int m = wm + i * 16 + lm;
      af[i] = *(const short8*)&lsA[m * 32 + (q ^ ((m >> 1) & 3)) * 8];
      int n = wn + i * 16 + lm;
      bfr[i] = *(const short8*)&lsB[n * 32 + (q ^ ((n >> 1) & 3)) * 8];
    }
    #pragma unroll
    for (int i = 0; i < 4; ++i)
      #pragma unroll
      for (int jj = 0; jj < 4; ++jj)
        acc[i][jj] = __builtin_amdgcn_mfma_f32_16x16x32_bf16(af[i], bfr[jj], acc[i][jj], 0, 0, 0);
    __syncthreads();
  }

  int colbase = by * 128;
  #pragma unroll
  for (int i = 0; i < 4; ++i)
    #pragma unroll
    for (int jj = 0; jj < 4; ++jj)
      #pragma unroll
      for (int reg = 0; reg < 4; ++reg) {
        int row = m0 + wm + i * 16 + q * 4 + reg;
        int col = colbase + wn + jj * 16 + lm;
        G[(size_t)row * 1536 + col] = acc[i][jj][reg];
      }
}

// ---------------- GRU elementwise + colsum(h_new) into cs_next ---------------------
__global__ __launch_bounds__(256) void gru_kernel(
    const float* __restrict__ G, float* __restrict__ h,
    __hip_bfloat16* __restrict__ hbf,
    const int* __restrict__ counts,
    const float* __restrict__ bc, const float* __restrict__ bih,
    const float* __restrict__ bhh, float* __restrict__ cs_next)
{
  int b = blockIdx.x;
  int g = b / NROWBLK, rb = b - g * NROWBLK;
  int t = threadIdx.x;
  float bc_r = bc[t], bc_z = bc[H + t], bc_n = bc[2 * H + t];
  float bih_r = bih[t], bih_z = bih[H + t], bih_n = bih[2 * H + t];
  float bhh_r = bhh[t], bhh_z = bhh[H + t], bhh_n = bhh[2 * H + t];
  float local = 0.f;
  for (int q = 0; q < 32; ++q) {
    int r = rb * 32 + q;
    if (r >= NP1) break;
    size_t rowoff = ((size_t)g * NP1 + r) * 1536;
    float deg = (r < NNODES) ? (float)counts[g * NNODES + r] : (float)NNODES;
    float ir  = G[rowoff + t]         + deg * bc_r + bih_r;
    float iz  = G[rowoff + H + t]     + deg * bc_z + bih_z;
    float in_ = G[rowoff + 2 * H + t] + deg * bc_n + bih_n;
    float hr  = G[rowoff + 3 * H + t] + bhh_r;
    float hz  = G[rowoff + 4 * H + t] + bhh_z;
    float hn  = G[rowoff + 5 * H + t] + bhh_n;
    float rg = 1.f / (1.f + expf(-(ir + hr)));
    float z  = 1.f / (1.f + expf(-(iz + hz)));
    float n  = tanhf(in_ + rg * hn);
    size_t hoff = ((size_t)g * NP1 + r) * H + t;
    float hp = h[hoff];
    float hnew = (1.f - z) * n + z * hp;
    h[hoff] = hnew;
    hbf[hoff] = __float2bfloat16(hnew);
    if (r < NNODES) local += hnew;
  }
  atomicAdd(&cs_next[g * H + t], local);
}

// ---------------- final logits + log_softmax ---------------------------------------
__global__ __launch_bounds__(256) void final_kernel(
    const float* __restrict__ h, const float* __restrict__ Wfc,
    const float* __restrict__ bfc, float* __restrict__ out)
{
  __shared__ float red0[256];
  __shared__ float red1[256];
  int t = threadIdx.x;
  float sn0 = h[(size_t)NNODES * H + t];              // b supernode
  float sn1 = h[((size_t)NP1 + NNODES) * H + t];      // a supernode
  red0[t] = sn0 * Wfc[t]       + sn1 * Wfc[H + t];
  red1[t] = sn0 * Wfc[512 + t] + sn1 * Wfc[512 + H + t];
  __syncthreads();
  for (int s = 128; s > 0; s >>= 1) {
    if (t < s) { red0[t] += red0[t + s]; red1[t] += red1[t + s]; }
    __syncthreads();
  }
  if (t == 0) {
    float l0 = red0[0] + bfc[0], l1 = red1[0] + bfc[1];
    float m = fmaxf(l0, l1);
    float lse = m + logf(expf(l0 - m) + expf(l1 - m));
    out[0] = l0 - lse;
    out[1] = l1 - lse;
  }
}

extern "C" void kernel_launch(void* const* d_in, const int* in_sizes, int n_in,
                              void* d_out, int out_size, void* d_ws, size_t ws_size,
                              hipStream_t stream) {
  const float* b_x   = (const float*)d_in[0];
  const float* b_adj = (const float*)d_in[1];
  const float* a_x   = (const float*)d_in[2];
  const float* a_adj = (const float*)d_in[3];
  const float* Wlin  = (const float*)d_in[4];
  const float* blin  = (const float*)d_in[5];
  const float* Wih   = (const float*)d_in[6];
  const float* bih   = (const float*)d_in[7];
  const float* Whh   = (const float*)d_in[8];
  const float* bhh   = (const float*)d_in[9];
  const float* Wfc   = (const float*)d_in[10];
  const float* bfc   = (const float*)d_in[11];
  float* out = (float*)d_out;

  char* ws = (char*)d_ws;
  size_t off = 0;
  auto alloc = [&](size_t bytes) {
    void* p = ws + off;
    off += (bytes + 255) & ~(size_t)255;
    return p;
  };
  float* h               = (float*)alloc((size_t)MTOT * H * 4);            // 16.4 MB
  __hip_bfloat16* hbf    = (__hip_bfloat16*)alloc((size_t)MPAD * H * 2);   // 8.3 MB
  __hip_bfloat16* haggbf = (__hip_bfloat16*)alloc((size_t)MPAD * H * 2);   // 8.3 MB
  float* G               = (float*)alloc((size_t)MPAD * 1536 * 4);         // 99.1 MB
  __hip_bfloat16* Wcat   = (__hip_bfloat16*)alloc((size_t)1536 * H * 2);   // 0.8 MB
  float* bc              = (float*)alloc((size_t)G3 * 4);
  int* colidx            = (int*)alloc((size_t)2 * NNODES * CAP * 4);      // 4.1 MB
  int* counts            = (int*)alloc((size_t)2 * NNODES * 4);
  float* cs              = (float*)alloc((size_t)(TSTEPS + 1) * 2 * H * 4);

  hipMemsetAsync(counts, 0, (size_t)2 * NNODES * 4, stream);
  hipMemsetAsync(cs, 0, (size_t)(TSTEPS + 1) * 2 * H * 4, stream);

  build_ell_kernel<<<125000, 256, 0, stream>>>(b_adj, a_adj, counts, colidx);
  weights_kernel<<<1536, 256, 0, stream>>>(Wih, Wlin, blin, Whh, Wcat, bc);
  init_h_kernel<<<2 * NROWBLK, 256, 0, stream>>>(b_x, a_x, h, hbf, cs);

  for (int t = 0; t < TSTEPS; ++t) {
    spmm_kernel<<<MTOT, 256, 0, stream>>>(hbf, haggbf, counts, colidx, cs + t * 2 * H);
    mfma_gemm_kernel<<<dim3(MPAD / 128, 12), 256, 0, stream>>>(haggbf, hbf, Wcat, G);
    gru_kernel<<<2 * NROWBLK, 256, 0, stream>>>(G, h, hbf, counts, bc, bih, bhh,
                                                cs + (t + 1) * 2 * H);
  }
  final_kernel<<<1, 256, 0, stream>>>(h, Wfc, bfc, out);
}